// Round 1
// baseline (45.698 us; speedup 1.0000x reference)
//
#include <hip/hip_runtime.h>
#include <hip/hip_bf16.h>

#define Bsz 2048
#define Dim 128
#define Nrows 4096

typedef float f32x4 __attribute__((ext_vector_type(4)));
typedef __bf16 bf16x8 __attribute__((ext_vector_type(8)));

// K0: normalize rows of [z; z_aug] -> bf16 U; per-block partials of
// w1 = sum_j labf_j * u_j, wall = sum_j u_j  (j over all 4096 rows, labels tiled)
__global__ __launch_bounds__(256) void k_norm(const float* __restrict__ z,
                                              const float* __restrict__ za,
                                              const long long* __restrict__ labels,
                                              __bf16* __restrict__ U,
                                              float* __restrict__ w1p,
                                              float* __restrict__ wallp) {
    const int wave = threadIdx.x >> 6, lane = threadIdx.x & 63;
    __shared__ float s1[4][128];
    __shared__ float s0[4][128];
    float a1x = 0.f, a1y = 0.f, a0x = 0.f, a0y = 0.f;
    #pragma unroll
    for (int pass = 0; pass < 4; pass++) {
        int r = blockIdx.x * 16 + pass * 4 + wave;
        const float* src = (r < Bsz) ? (z + (size_t)r * Dim) : (za + (size_t)(r - Bsz) * Dim);
        float2 x = reinterpret_cast<const float2*>(src)[lane];
        float ss = x.x * x.x + x.y * x.y;
        #pragma unroll
        for (int m = 1; m < 64; m <<= 1) ss += __shfl_xor(ss, m);
        float n = sqrtf(ss);
        float sc = 1.0f / fmaxf(n, 1e-12f);
        float u0 = x.x * sc, u1 = x.y * sc;
        U[(size_t)r * Dim + 2 * lane]     = (__bf16)u0;
        U[(size_t)r * Dim + 2 * lane + 1] = (__bf16)u1;
        float lf = (labels[r & (Bsz - 1)] == 1) ? 1.f : 0.f;
        a0x += u0; a0y += u1;
        a1x += lf * u0; a1y += lf * u1;
    }
    s1[wave][2 * lane] = a1x; s1[wave][2 * lane + 1] = a1y;
    s0[wave][2 * lane] = a0x; s0[wave][2 * lane + 1] = a0y;
    __syncthreads();
    int t = threadIdx.x;
    if (t < 128) {
        w1p[blockIdx.x * 128 + t]   = s1[0][t] + s1[1][t] + s1[2][t] + s1[3][t];
        wallp[blockIdx.x * 128 + t] = s0[0][t] + s0[1][t] + s0[2][t] + s0[3][t];
    }
}

// K2: reduce the 256 block-partials into w1/wall; count labels==1
__global__ __launch_bounds__(1024) void k_wreduce(const float* __restrict__ w1p,
                                                  const float* __restrict__ wallp,
                                                  const long long* __restrict__ labels,
                                                  float* __restrict__ w1,
                                                  float* __restrict__ wall,
                                                  int* __restrict__ count1) {
    __shared__ float buf1[8][128];
    __shared__ float buf0[8][128];
    __shared__ int cbuf[1024];
    int t = threadIdx.x;
    int d = t & 127, h = t >> 7;
    float s1v = 0.f, s0v = 0.f;
    #pragma unroll
    for (int k = 0; k < 32; k++) {
        int b = h * 32 + k;
        s1v += w1p[b * 128 + d];
        s0v += wallp[b * 128 + d];
    }
    buf1[h][d] = s1v; buf0[h][d] = s0v;
    cbuf[t] = (int)labels[t] + (int)labels[t + 1024];
    __syncthreads();
    if (t < 128) {
        float r1 = 0.f, r0 = 0.f;
        #pragma unroll
        for (int hh = 0; hh < 8; hh++) { r1 += buf1[hh][t]; r0 += buf0[hh][t]; }
        w1[t] = r1; wall[t] = r0;
    }
    for (int s = 512; s > 0; s >>= 1) {
        if (t < s) cbuf[t] += cbuf[t + s];
        __syncthreads();
    }
    if (t == 0) *count1 = cbuf[0];
}

// K3: the heavy kernel. For each row i: denom_i = sum_{j!=i} exp(S_ij - 2),
// S = 2 * U U^T (bf16 MFMA). Each wave: 64 rows (A resident in regs) x 64-col strip.
// Partials written to part[row*64 + strip]; fixed order => deterministic.
__global__ __launch_bounds__(256) void k_denom(const __bf16* __restrict__ U,
                                               float* __restrict__ part) {
    const int rowblk = blockIdx.x >> 4;   // 0..63
    const int jchunk = blockIdx.x & 15;   // 0..15
    const int wave = threadIdx.x >> 6;
    const int lane = threadIdx.x & 63;
    const int strip = jchunk * 4 + wave;  // 0..63
    const int rowbase = rowblk * 64;
    const int l15 = lane & 15, l4 = lane >> 4;

    // A fragments: 4 row-frags x 4 k-steps, resident for the whole strip loop
    bf16x8 a[4][4];
    #pragma unroll
    for (int rf = 0; rf < 4; rf++)
        #pragma unroll
        for (int ks = 0; ks < 4; ks++)
            a[rf][ks] = *reinterpret_cast<const bf16x8*>(
                U + (size_t)(rowbase + rf * 16 + l15) * Dim + ks * 32 + l4 * 8);

    float dsum[4][4] = {{0.f}};
    const bool diagS = (strip == rowblk);
    const float C1 = 2.0f, C0 = -2.0f;  // exp arg = 2*acc - 2

    #pragma unroll
    for (int t = 0; t < 4; t++) {
        const int jb = strip * 64 + t * 16;
        bf16x8 b[4];
        #pragma unroll
        for (int ks = 0; ks < 4; ks++)
            b[ks] = *reinterpret_cast<const bf16x8*>(
                U + (size_t)(jb + l15) * Dim + ks * 32 + l4 * 8);
        #pragma unroll
        for (int rf = 0; rf < 4; rf++) {
            f32x4 acc = {0.f, 0.f, 0.f, 0.f};
            #pragma unroll
            for (int ks = 0; ks < 4; ks++)
                acc = __builtin_amdgcn_mfma_f32_16x16x32_bf16(a[rf][ks], b[ks], acc, 0, 0, 0);
            const bool dg = diagS && (t == rf);
            #pragma unroll
            for (int q = 0; q < 4; q++) {
                float e = __expf(fmaf(acc[q], C1, C0));
                if (dg && (l15 == l4 * 4 + q)) e = 0.f;  // exclude j == i
                dsum[rf][q] += e;
            }
        }
    }

    // reduce over the 16 cols held by lanes sharing (lane>>4); C layout:
    // col = lane&15, row = (lane>>4)*4 + q  [HW-verified mapping]
    #pragma unroll
    for (int rf = 0; rf < 4; rf++) {
        #pragma unroll
        for (int q = 0; q < 4; q++) {
            float v = dsum[rf][q];
            v += __shfl_xor(v, 1);
            v += __shfl_xor(v, 2);
            v += __shfl_xor(v, 4);
            v += __shfl_xor(v, 8);
            if (l15 == 0)
                part[(size_t)(rowbase + rf * 16 + l4 * 4 + q) * 64 + strip] = v;
        }
    }
}

// K4: per-row finalize. One wave per row.
__global__ __launch_bounds__(256) void k_row(const __bf16* __restrict__ U,
                                             const float* __restrict__ part,
                                             const float* __restrict__ w1,
                                             const float* __restrict__ wall,
                                             const long long* __restrict__ labels,
                                             const int* __restrict__ count1p,
                                             float* __restrict__ contrib,
                                             float* __restrict__ unsupA) {
    const int wave = threadIdx.x >> 6, lane = threadIdx.x & 63;
    const int i = blockIdx.x * 4 + wave;
    const int partner = (i < Bsz) ? i + Bsz : i - Bsz;

    float dn = part[(size_t)i * 64 + lane];
    float u0 = (float)U[(size_t)i * Dim + 2 * lane];
    float u1 = (float)U[(size_t)i * Dim + 2 * lane + 1];
    float p0 = (float)U[(size_t)partner * Dim + 2 * lane];
    float p1 = (float)U[(size_t)partner * Dim + 2 * lane + 1];
    float w1a = w1[2 * lane], w1b = w1[2 * lane + 1];
    float wa  = wall[2 * lane], wb = wall[2 * lane + 1];

    float d1 = u0 * w1a + u1 * w1b;   // u . w1
    float da = u0 * wa + u1 * wb;     // u . wall
    float ds = u0 * u0 + u1 * u1;     // u . u  (S_ii / 2)
    float dp = u0 * p0 + u1 * p1;     // u . partner
    #pragma unroll
    for (int m = 1; m < 64; m <<= 1) {
        dn += __shfl_xor(dn, m);
        d1 += __shfl_xor(d1, m);
        da += __shfl_xor(da, m);
        ds += __shfl_xor(ds, m);
        dp += __shfl_xor(dp, m);
    }
    if (lane == 0) {
        const long long lb = labels[i & (Bsz - 1)];
        const int c1 = *count1p;
        const float cnt = 2.0f * (float)((lb == 1) ? c1 : (Bsz - c1));
        const float sii = 2.f * ds;
        const float sumeq = ((lb == 1) ? 2.f * d1 : 2.f * (da - d1)) - sii;
        const float lnD = logf(dn) + 2.0f;   // lse over j != i (mx-invariant)
        const float uns = lnD - 2.f * dp;
        const float sup = lnD - sumeq / (cnt - 1.0f);
        contrib[i] = (lb == 1) ? sup : uns;
        unsupA[i] = uns;
    }
}

// K5: deterministic tree reduction to the scalar loss.
__global__ __launch_bounds__(256) void k_final(const float* __restrict__ contrib,
                                               const float* __restrict__ unsupA,
                                               const int* __restrict__ count1p,
                                               float* __restrict__ out) {
    __shared__ float sc[256];
    __shared__ float su[256];
    int t = threadIdx.x;
    float c = 0.f, u = 0.f;
    for (int k = t; k < Nrows; k += 256) { c += contrib[k]; u += unsupA[k]; }
    sc[t] = c; su[t] = u;
    __syncthreads();
    for (int s = 128; s > 0; s >>= 1) {
        if (t < s) { sc[t] += sc[t + s]; su[t] += su[t + s]; }
        __syncthreads();
    }
    if (t == 0) {
        int c1 = *count1p;
        out[0] = ((c1 > 0) ? sc[0] : su[0]) / (float)Nrows;
    }
}

extern "C" void kernel_launch(void* const* d_in, const int* in_sizes, int n_in,
                              void* d_out, int out_size, void* d_ws, size_t ws_size,
                              hipStream_t stream) {
    const float* z  = (const float*)d_in[0];
    const float* za = (const float*)d_in[1];
    const long long* labels = (const long long*)d_in[2];

    char* ws = (char*)d_ws;
    __bf16* U      = (__bf16*)(ws);                 // 4096*128*2 = 1,048,576 B
    float*  part   = (float*)(ws + 1048576);        // 4096*64*4  = 1,048,576 B
    float*  w1p    = (float*)(ws + 2097152);        // 256*128*4  = 131,072 B
    float*  wallp  = (float*)(ws + 2228224);        // 131,072 B
    float*  w1     = (float*)(ws + 2359296);        // 512 B
    float*  wall   = (float*)(ws + 2359808);        // 512 B
    int*    count1 = (int*)  (ws + 2360320);        // (padded to 512 B)
    float*  contrib= (float*)(ws + 2360832);        // 16,384 B
    float*  unsupA = (float*)(ws + 2377216);        // 16,384 B -> end ~2.29 MB
    float*  out = (float*)d_out;

    hipLaunchKernelGGL(k_norm,    dim3(256),  dim3(256),  0, stream, z, za, labels, U, w1p, wallp);
    hipLaunchKernelGGL(k_wreduce, dim3(1),    dim3(1024), 0, stream, w1p, wallp, labels, w1, wall, count1);
    hipLaunchKernelGGL(k_denom,   dim3(1024), dim3(256),  0, stream, U, part);
    hipLaunchKernelGGL(k_row,     dim3(1024), dim3(256),  0, stream, U, part, w1, wall, labels, count1, contrib, unsupA);
    hipLaunchKernelGGL(k_final,   dim3(1),    dim3(256),  0, stream, contrib, unsupA, count1, out);
}